// Round 3
// baseline (248.279 us; speedup 1.0000x reference)
//
#include <hip/hip_runtime.h>
#include <math.h>

#define DD 128          // embed dim
#define DEG 16          // neighbors
#define TM 16           // node tile per block (grid = 50000/16 = 3125 exactly)
#define LDST 136        // LDS row stride in f16
#define EPSV 1e-5f

typedef _Float16 half4_t __attribute__((ext_vector_type(4)));
typedef _Float16 half8_t __attribute__((ext_vector_type(8)));
typedef float    f32x4   __attribute__((ext_vector_type(4)));
typedef signed char char8_t __attribute__((ext_vector_type(8)));

// fast tanh(n)/n, n >= EPSV. __expf maps to v_exp_f32; graceful at large n.
__device__ __forceinline__ float fast_tanh_over(float n) {
    float e  = __expf(2.f * n);
    float th = 1.f - __fdividef(2.f, e + 1.f);
    return __fdividef(th, n);
}
// fast atanh(n)/n, n in [EPSV, 1-EPSV]
__device__ __forceinline__ float fast_atanh_over(float n) {
    float r = 0.5f * __logf(__fdividef(1.f + n, 1.f - n));
    return __fdividef(r, n);
}

// ---- prep: x16[s] = x[s]*mask[s]^2 (f16), plus W->f16 transpose.
__global__ void prep(const float* __restrict__ x, const float* __restrict__ mask,
                     _Float16* __restrict__ x16, int n4, int xb,
                     const float* __restrict__ Wp, const float* __restrict__ Wn,
                     _Float16* __restrict__ WT)
{
    if ((int)blockIdx.x < xb) {
        int i = blockIdx.x * blockDim.x + threadIdx.x;
        if (i >= n4) return;
        float m = mask[i >> 5];            // 32 half4 groups per row
        float m2 = m * m;
        float4 v = ((const float4*)x)[i];
        half4_t h;
        h[0] = (_Float16)(v.x * m2); h[1] = (_Float16)(v.y * m2);
        h[2] = (_Float16)(v.z * m2); h[3] = (_Float16)(v.w * m2);
        ((half4_t*)x16)[i] = h;
    } else {
        int bid   = blockIdx.x - xb;
        int mat   = bid >> 3;              // 0..3: [l0p, l0n, l1p, l1n]
        int chunk = bid & 7;
        int l = mat >> 1, rel = mat & 1;
        const float* __restrict__ src = (rel ? Wn : Wp) + (size_t)l * DD * DD;
        _Float16* __restrict__ dst = WT + (size_t)mat * DD * DD;
        for (int o = chunk * 2048 + threadIdx.x; o < chunk * 2048 + 2048; o += 256) {
            int nn = o >> 7, kk = o & 127;
            dst[o] = (_Float16)src[kk * DD + nn];   // WT[n][k] (transposed)
        }
    }
}

// ---- per-column absmax of f16 [n][128] -> cmax (f32 bits in uint, atomicMax) ----
__global__ void colmax_k(const _Float16* __restrict__ src,
                         unsigned* __restrict__ cmax, int n)
{
    __shared__ float red[256];
    const int c  = threadIdx.x & 127;
    const int r0 = threadIdx.x >> 7;
    float m = 0.f;
    for (int r = blockIdx.x * 2 + r0; r < n; r += gridDim.x * 2)
        m = fmaxf(m, fabsf((float)src[(size_t)r * DD + c]));
    red[threadIdx.x] = m;
    __syncthreads();
    if (threadIdx.x < 128) {
        m = fmaxf(red[threadIdx.x], red[threadIdx.x + 128]);
        atomicMax(&cmax[c], __float_as_uint(m));   // values >= 0: uint order == float order
    }
}

// ---- quantize f16 -> int8 with per-column scale 127/colmax ----
__global__ void quant_k(const _Float16* __restrict__ src,
                        const unsigned* __restrict__ cmaxu,
                        uint2* __restrict__ dst8, int ngrp)   // ngrp = n*128/8
{
    int i = blockIdx.x * 256 + threadIdx.x;
    if (i >= ngrp) return;
    half8_t h = ((const half8_t*)src)[i];
    const float4 c0 = ((const float4*)cmaxu)[(i & 15) * 2];       // bits are f32
    const float4 c1 = ((const float4*)cmaxu)[(i & 15) * 2 + 1];
    float cm[8] = {c0.x, c0.y, c0.z, c0.w, c1.x, c1.y, c1.z, c1.w};
    int q[8];
    #pragma unroll
    for (int c = 0; c < 8; ++c) {
        float qs = __fdividef(127.f, fmaxf(cm[c], 1e-20f));
        float f  = (float)h[c] * qs;
        q[c] = __float2int_rn(fminf(fmaxf(f, -127.f), 127.f));
    }
    unsigned lo = (q[0] & 255) | ((q[1] & 255) << 8) | ((q[2] & 255) << 16) | ((unsigned)(q[3] & 255) << 24);
    unsigned hi = (q[4] & 255) | ((q[5] & 255) << 8) | ((q[6] & 255) << 16) | ((unsigned)(q[7] & 255) << 24);
    dst8[i] = make_uint2(lo, hi);
}

// ---- one fused GNN layer, int8 gather ----
// Gather rows are int8 (128 B = ONE cache line/row vs f16's two). R0/R1/R2
// showed per-wave MLP depth is irrelevant: throughput is capped by a per-CU
// in-flight-line budget (~26 lines, latency*BW fit). Halving lines/row is the
// only lever -> int8 with per-column scales, dequant folded in post-aggregate.
__global__ __launch_bounds__(256, 2) void fused_layer(
    const signed char* __restrict__ src8,        // int8, column-scaled
    const unsigned*    __restrict__ cmaxu,       // 128 col absmax (f32 bits)
    const int*   __restrict__ adj, const float* __restrict__ wgt,
    const float* __restrict__ mask,
    const _Float16* __restrict__ WTp, const _Float16* __restrict__ WTn,
    float* __restrict__ dst_f32, _Float16* __restrict__ dst_f16,
    int n, int apply_logmap)
{
    __shared__ __align__(16) _Float16 aggP[TM][LDST];   // 4.25 KB
    __shared__ __align__(16) _Float16 aggN[TM][LDST];   // 4.25 KB
    __shared__ float partA[4][TM];
    __shared__ float partB[4][TM];

    const int row0 = blockIdx.x * TM;
    const int tid  = threadIdx.x;
    const int qw   = tid >> 4;         // owns node row qw
    const int l16  = tid & 15;         // covers cols [8*l16, 8*l16+8)

    // dequant factors for this lane's 8 columns
    const float4 dc0 = ((const float4*)cmaxu)[l16 * 2];
    const float4 dc1 = ((const float4*)cmaxu)[l16 * 2 + 1];
    const float ds[8] = {dc0.x * (1.f/127.f), dc0.y * (1.f/127.f),
                         dc0.z * (1.f/127.f), dc0.w * (1.f/127.f),
                         dc1.x * (1.f/127.f), dc1.y * (1.f/127.f),
                         dc1.z * (1.f/127.f), dc1.w * (1.f/127.f)};

    // ---- phase 1: gather-aggregate (8 B/lane, one line per row) ----
    float aP[8] = {0.f,0.f,0.f,0.f,0.f,0.f,0.f,0.f};
    float aN[8] = {0.f,0.f,0.f,0.f,0.f,0.f,0.f,0.f};
    const int node = row0 + qw;
    if (node < n) {
        const int*   __restrict__ arow = adj + (size_t)node * DEG;
        const float* __restrict__ wrow = wgt + (size_t)node * DEG;
        int   idxs[16];
        float ws[16];
        #pragma unroll
        for (int b = 0; b < 4; ++b) {
            int4   ia = ((const int4*)arow)[b];
            float4 wa = ((const float4*)wrow)[b];
            idxs[b*4+0] = ia.x; idxs[b*4+1] = ia.y; idxs[b*4+2] = ia.z; idxs[b*4+3] = ia.w;
            ws[b*4+0] = wa.x; ws[b*4+1] = wa.y; ws[b*4+2] = wa.z; ws[b*4+3] = wa.w;
        }
        char8_t v[16];
        #pragma unroll
        for (int j = 0; j < 16; ++j)
            v[j] = *(const char8_t*)(src8 + (size_t)idxs[j] * DD + l16 * 8);
        #pragma unroll
        for (int j = 0; j < 16; ++j) {
            float wp = fmaxf(ws[j], 0.f);
            float wn = fmaxf(-ws[j], 0.f);
            #pragma unroll
            for (int c = 0; c < 8; ++c) {
                float f = (float)v[j][c];
                aP[c] += wp * f;
                aN[c] += wn * f;
            }
        }
    }
    half8_t hP, hN;
    #pragma unroll
    for (int c = 0; c < 8; ++c) {
        hP[c] = (_Float16)(aP[c] * ds[c]);
        hN[c] = (_Float16)(aN[c] * ds[c]);
    }
    *(half8_t*)&aggP[qw][l16 * 8] = hP;
    *(half8_t*)&aggN[qw][l16 * 8] = hN;
    __syncthreads();

    // ---- phase 2: MFMA. 4 waves split the 8 n-blocks (2 each) ----
    const int wv2  = tid >> 6;
    const int l64  = tid & 63;
    const int l15  = l64 & 15;
    const int quad = l64 >> 4;

    half8_t aPf[4], aNf[4];
    #pragma unroll
    for (int kb = 0; kb < 4; ++kb) {
        aPf[kb] = *(const half8_t*)&aggP[l15][kb * 32 + quad * 8];
        aNf[kb] = *(const half8_t*)&aggN[l15][kb * 32 + quad * 8];
    }

    f32x4 acc[2];
    acc[0] = (f32x4){0.f, 0.f, 0.f, 0.f};
    acc[1] = (f32x4){0.f, 0.f, 0.f, 0.f};
    #pragma unroll
    for (int t = 0; t < 2; ++t) {
        const int nb = wv2 * 2 + t;
        const _Float16* bp = WTp + (size_t)(nb * 16 + l15) * DD + quad * 8;
        const _Float16* bn = WTn + (size_t)(nb * 16 + l15) * DD + quad * 8;
        #pragma unroll
        for (int kb = 0; kb < 4; ++kb) {
            acc[t] = __builtin_amdgcn_mfma_f32_16x16x32_f16(
                aPf[kb], *(const half8_t*)(bp + kb * 32), acc[t], 0, 0, 0);
            acc[t] = __builtin_amdgcn_mfma_f32_16x16x32_f16(
                aNf[kb], *(const half8_t*)(bn + kb * 32), acc[t], 0, 0, 0);
        }
    }

    // ---- phase 3: epilogue. C/D: row=quad*4+r, cols wv2*32 + {l15, 16+l15} ----
    float cv0[4], cv1[4], mr[4];
    #pragma unroll
    for (int r = 0; r < 4; ++r) {
        const int rl  = quad * 4 + r;
        const int row = row0 + rl;
        float m = (row < n) ? mask[row] : 0.f;
        mr[r] = m;
        float c0 = acc[0][r] * m, c1 = acc[1][r] * m;
        cv0[r] = c0; cv1[r] = c1;
        float p = c0 * c0 + c1 * c1;
        p += __shfl_xor(p, 1); p += __shfl_xor(p, 2);
        p += __shfl_xor(p, 4); p += __shfl_xor(p, 8);
        if (l15 == 0) partA[wv2][rl] = p;
    }
    __syncthreads();

    float x0[4], x1[4];
    #pragma unroll
    for (int r = 0; r < 4; ++r) {
        const int rl = quad * 4 + r;
        float c2 = partA[0][rl] + partA[1][rl] + partA[2][rl] + partA[3][rl];
        float nc = fmaxf(sqrtf(c2), EPSV);
        float sc = fast_tanh_over(nc);
        float m  = mr[r];
        float t0 = fmaxf(cv0[r] * sc * m, 0.f) * m;
        float t1 = fmaxf(cv1[r] * sc * m, 0.f) * m;
        x0[r] = t0; x1[r] = t1;
        if (apply_logmap) {
            float p = t0 * t0 + t1 * t1;
            p += __shfl_xor(p, 1); p += __shfl_xor(p, 2);
            p += __shfl_xor(p, 4); p += __shfl_xor(p, 8);
            if (l15 == 0) partB[wv2][rl] = p;
        }
    }

    if (apply_logmap) {
        __syncthreads();
        #pragma unroll
        for (int r = 0; r < 4; ++r) {
            const int rl  = quad * 4 + r;
            const int row = row0 + rl;
            if (row >= n) continue;
            float s2  = partB[0][rl] + partB[1][rl] + partB[2][rl] + partB[3][rl];
            float nc2 = fminf(fmaxf(sqrtf(s2), EPSV), 1.f - EPSV);
            float f = fast_atanh_over(nc2) * mr[r] * mr[r];
            _Float16* drow = dst_f16 + (size_t)row * DD + wv2 * 32 + l15;
            drow[0]  = (_Float16)(x0[r] * f);
            drow[16] = (_Float16)(x1[r] * f);
        }
    } else {
        #pragma unroll
        for (int r = 0; r < 4; ++r) {
            const int rl  = quad * 4 + r;
            const int row = row0 + rl;
            if (row >= n) continue;
            float* drow = dst_f32 + (size_t)row * DD + wv2 * 32 + l15;
            drow[0]  = x0[r];
            drow[16] = x1[r];
        }
    }
}

extern "C" void kernel_launch(void* const* d_in, const int* in_sizes, int n_in,
                              void* d_out, int out_size, void* d_ws, size_t ws_size,
                              hipStream_t stream)
{
    const float* node_repr = (const float*)d_in[0];
    const int*   adj       = (const int*)  d_in[1];
    const float* weight    = (const float*)d_in[2];
    const float* mask      = (const float*)d_in[3];
    const float* W_pos     = (const float*)d_in[4];   // [L,128,128]
    const float* W_neg     = (const float*)d_in[5];

    const int n = in_sizes[0] / DD;                   // 50000

    // workspace: bufA f16 (x16 then y16) | buf8 int8 (x8 then y8) | WT | cmax
    unsigned char* ws = (unsigned char*)d_ws;
    _Float16*    bufA  = (_Float16*)ws;                              // n*128*2 B
    signed char* buf8  = (signed char*)(ws + (size_t)n * DD * 2);    // n*128   B
    _Float16*    WT    = (_Float16*)(ws + (size_t)n * DD * 3);       // 128 KB
    unsigned*    cmaxX = (unsigned*)(ws + (size_t)n * DD * 3 + (size_t)4 * DD * DD * 2);
    unsigned*    cmaxY = cmaxX + DD;

    hipMemsetAsync(cmaxX, 0, 2 * DD * sizeof(unsigned), stream);

    const int n4 = n * DD / 4;
    const int xb = (n4 + 255) / 256;
    prep<<<xb + 32, 256, 0, stream>>>(node_repr, mask, bufA, n4, xb,
                                      W_pos, W_neg, WT);

    const int ngrp = n * DD / 8;
    const int qb   = (ngrp + 255) / 256;
    dim3 grid((n + TM - 1) / TM);

    // layer 1: quantize x, gather int8, write y16 (logmap*mask^2, f16)
    colmax_k<<<256, 256, 0, stream>>>(bufA, cmaxX, n);
    quant_k<<<qb, 256, 0, stream>>>(bufA, cmaxX, (uint2*)buf8, ngrp);
    fused_layer<<<grid, 256, 0, stream>>>(buf8, cmaxX, adj, weight, mask,
                                          WT + 0 * DD * DD, WT + 1 * DD * DD,
                                          nullptr, bufA, n, 1);
    // layer 2: quantize y, gather int8, write f32 output
    colmax_k<<<256, 256, 0, stream>>>(bufA, cmaxY, n);
    quant_k<<<qb, 256, 0, stream>>>(bufA, cmaxY, (uint2*)buf8, ngrp);
    fused_layer<<<grid, 256, 0, stream>>>(buf8, cmaxY, adj, weight, mask,
                                          WT + 2 * DD * DD, WT + 3 * DD * DD,
                                          (float*)d_out, nullptr, n, 0);
}